// Round 4
// baseline (768.791 us; speedup 1.0000x reference)
//
#include <hip/hip_runtime.h>
#include <hip/hip_bf16.h>

// MoE E=64, top-2, T=8192, D=1024, DFF=1408. Round 4:
//  - ffn tiles 128x64 (fewer acc regs) -> 3-4 blocks/CU occupancy
//  - XOR-swizzled LDS granules (conflict-free staging writes)
//  - XCD-clustered block swizzle (A-panel L2 locality)
//  - gate v2: 8 tokens/block (identical FP order, 8x less Wg traffic)

#define S_ 2048
#define B_ 4
#define D_ 1024
#define DFF_ 1408
#define E_ 64
#define T_ 8192
#define KTOP_ 2
#define NPAIR_ (T_*KTOP_)
#define PAD_ 384
#define ROWS_ (E_*PAD_)

#define BM 128
#define BN 64
#define BK 32

typedef __attribute__((ext_vector_type(8))) short short8;
typedef __attribute__((ext_vector_type(4))) float f32x4;
typedef __attribute__((ext_vector_type(4))) unsigned short us4;

// ---------------- workspace layout (bytes) ----------------
constexpr size_t OFF_PROBS  = 0;
constexpr size_t OFF_PE     = OFF_PROBS + (size_t)T_*E_*4;
constexpr size_t OFF_PW     = OFF_PE + (size_t)NPAIR_*4;
constexpr size_t OFF_COUNTS = OFF_PW + (size_t)NPAIR_*4;
constexpr size_t OFF_CURSOR = OFF_COUNTS + 256;
constexpr size_t OFF_MESUM  = OFF_CURSOR + 256;
constexpr size_t OFF_ROWTOK = OFF_MESUM + 256;
constexpr size_t OFF_ROWW   = OFF_ROWTOK + (size_t)ROWS_*4;
constexpr size_t OFF_XBUF   = OFF_ROWW + (size_t)ROWS_*4;
constexpr size_t OFF_H      = OFF_XBUF + (size_t)ROWS_*D_*2;

__device__ __forceinline__ short f2bfs(float f) {
  union { __hip_bfloat16 h; short s; } u;
  u.h = __float2bfloat16(f);
  return u.s;
}

// granule XOR swizzle: g in [0,64), key = kseg bits -> spreads bank classes
__device__ __forceinline__ int SWZ(int g) { return g ^ (((g >> 4) & 3) << 1); }

// ---------------- gate v2: 8 tokens/block, wave owns 2 tokens ----------------
__device__ __forceinline__ float softmax64(float acc, int lane) {
  float m = acc;
  for (int o = 32; o; o >>= 1) m = fmaxf(m, __shfl_xor(m, o));
  float p = expf(acc - m);
  float s = p;
  for (int o = 32; o; o >>= 1) s += __shfl_xor(s, o);
  return p / s;
}

__device__ __forceinline__ void topk_write(float p, int t, int lane,
    float* __restrict__ probs, int* __restrict__ pe, float* __restrict__ pw,
    int* __restrict__ counts) {
  probs[(size_t)t * E_ + lane] = p;
  float v1 = p; int i1 = lane;
  for (int o = 32; o; o >>= 1) {
    float ov = __shfl_xor(v1, o); int oi = __shfl_xor(i1, o);
    if (ov > v1 || (ov == v1 && oi < i1)) { v1 = ov; i1 = oi; }
  }
  float v2 = (lane == i1) ? -1.f : p; int i2 = lane;
  for (int o = 32; o; o >>= 1) {
    float ov = __shfl_xor(v2, o); int oi = __shfl_xor(i2, o);
    if (ov > v2 || (ov == v2 && oi < i2)) { v2 = ov; i2 = oi; }
  }
  if (lane == 0) {
    float wsum = v1 + v2;
    pe[2 * t]     = i1; pw[2 * t]     = v1 / wsum;
    pe[2 * t + 1] = i2; pw[2 * t + 1] = v2 / wsum;
    atomicAdd(&counts[i1], 1);
    atomicAdd(&counts[i2], 1);
  }
}

__global__ __launch_bounds__(256) void gate_kernel(
    const float* __restrict__ x, const float* __restrict__ Wg,
    float* __restrict__ probs, int* __restrict__ pe, float* __restrict__ pw,
    int* __restrict__ counts) {
  int t0 = blockIdx.x * 8;
  int tid = threadIdx.x;
  int lane = tid & 63, wv = tid >> 6;
  __shared__ float tk[8][D_];
  for (int u = tid; u < 8 * (D_ / 4); u += 256) {
    int r = u >> 8, c4 = u & 255;
    int t = t0 + r;
    int b = t >> 11, s = t & (S_ - 1);
    ((float4*)tk[r])[c4] = ((const float4*)(x + (size_t)(s * B_ + b) * D_))[c4];
  }
  __syncthreads();
  const float* tkA = tk[2 * wv];
  const float* tkB = tk[2 * wv + 1];
  float acc0 = 0.f, acc1 = 0.f;
  #pragma unroll 8
  for (int d = 0; d < D_; ++d) {
    float w = Wg[(size_t)d * E_ + lane];
    acc0 += tkA[d] * w;
    acc1 += tkB[d] * w;
  }
  int ta = t0 + 2 * wv, tb = ta + 1;
  float p0 = softmax64(acc0, lane);
  float p1 = softmax64(acc1, lane);
  topk_write(p0, ta, lane, probs, pe, pw, counts);
  topk_write(p1, tb, lane, probs, pe, pw, counts);
}

// ---------------- me reduce ----------------
__global__ __launch_bounds__(256) void me_kernel(const float* __restrict__ probs,
                                                 float* __restrict__ mesum) {
  int e = blockIdx.x, tid = threadIdx.x;
  float a = 0.f;
  for (int t = tid; t < T_; t += 256) a += probs[(size_t)t * E_ + e];
  __shared__ float red[256];
  red[tid] = a; __syncthreads();
  for (int s = 128; s; s >>= 1) {
    if (tid < s) red[tid] += red[tid + s];
    __syncthreads();
  }
  if (tid == 0) mesum[e] = red[0];
}

// ---------------- finalize l_aux ----------------
__global__ __launch_bounds__(64) void finalize_kernel(
    const int* __restrict__ counts, const float* __restrict__ mesum,
    float* __restrict__ laux_out) {
  int lane = threadIdx.x;
  float contrib = (mesum[lane] / (float)T_) * ((float)counts[lane] / (float)(T_ * KTOP_));
  for (int o = 32; o; o >>= 1) contrib += __shfl_xor(contrib, o);
  if (lane == 0) laux_out[0] = (float)E_ * contrib;
}

// ---------------- scatter ----------------
__global__ __launch_bounds__(64) void scatter_kernel(
    const float* __restrict__ x, const int* __restrict__ pe, const float* __restrict__ pw,
    int* __restrict__ cursor, int* __restrict__ rowtok, float* __restrict__ roww,
    unsigned short* __restrict__ xbuf) {
  int p = blockIdx.x;
  int lane = threadIdx.x;
  __shared__ int srow;
  if (lane == 0) {
    int e = pe[p];
    int slot = atomicAdd(&cursor[e], 1);
    int row = (slot < PAD_) ? (e * PAD_ + slot) : -1;
    if (row >= 0) { rowtok[row] = p >> 1; roww[row] = pw[p]; }
    srow = row;
  }
  __syncthreads();
  int row = srow;
  if (row < 0) return;
  int t = p >> 1;
  int b = t >> 11, s = t & (S_ - 1);
  const float4* src = (const float4*)(x + (size_t)(s * B_ + b) * D_);
  unsigned short* dst = xbuf + (size_t)row * D_;
  for (int i = lane; i < D_ / 4; i += 64) {
    float4 v = src[i];
    us4 o;
    o.x = (unsigned short)f2bfs(v.x); o.y = (unsigned short)f2bfs(v.y);
    o.z = (unsigned short)f2bfs(v.z); o.w = (unsigned short)f2bfs(v.w);
    *(us4*)(dst + i * 4) = o;
  }
}

// ---------------- ffn1: h = silu(x@W1) * (x@W3), 128x64 tile ----------------
__global__ __launch_bounds__(256, 3) void ffn1_kernel(
    const unsigned short* __restrict__ xbuf, const float* __restrict__ W1,
    const float* __restrict__ W3, const int* __restrict__ counts,
    unsigned short* __restrict__ h) {
  // XCD-clustered decode: grid 4224 = 192 groups (e,y) x 22 n-blocks
  int bid = blockIdx.x;
  int u = bid >> 3, r = bid & 7;
  int ni_blk = u % 22;
  int g = (u / 22) * 8 + r;          // 0..191
  int ymb = g % 3, e = g / 3;
  int m0 = ymb * BM;
  int n0 = ni_blk * BN;

  int Me = min(counts[e], PAD_);
  if (m0 >= Me) return;

  const unsigned short* A = xbuf + (size_t)(e * PAD_ + m0) * D_;
  const float* B1 = W1 + (size_t)e * D_ * DFF_ + n0;
  const float* B3 = W3 + (size_t)e * D_ * DFF_ + n0;
  unsigned short* hptr = h + (size_t)e * PAD_ * DFF_;

  __shared__ short Als[BM * BK];   // 8KB: 8 subtiles (16 rows x 32 k)
  __shared__ short B1s[BK * BN];   // 4KB: 4 subtiles
  __shared__ short B3s[BK * BN];   // 4KB

  int tid = threadIdx.x;
  int lane = tid & 63;
  int wv = tid >> 6, wr = wv >> 1, wc = wv & 1;

  // A staging: thread (arow=tid>>2 in 0..63 (+64), akseg=tid&3)
  int arow = tid >> 2, akseg = tid & 3;
  int ag = (akseg << 4) + (arow & 15);
  int aoff0 = ((arow >> 4) << 10) + (SWZ(ag) << 4);
  int aoff1 = aoff0 + (4 << 10);
  // B staging: wave wv = k-quarter, lane = column
  int bc = lane, bks = wv;
  int bg = (bks << 4) + (bc & 15);
  int boff = ((bc >> 4) << 10) + (SWZ(bg) << 4);

  const unsigned short* qa0 = A + (size_t)arow * D_ + akseg * 8;
  const unsigned short* qa1 = A + (size_t)(arow + 64) * D_ + akseg * 8;
  const float* q1 = B1 + (size_t)(bks * 8) * DFF_ + bc;
  const float* q3 = B3 + (size_t)(bks * 8) * DFF_ + bc;

  short8 av0, av1;
  float f1[8], f3[8];
  f32x4 acc1[4][2] = {};
  f32x4 acc3[4][2] = {};

#define F1_LOAD() do {                                                   \
    av0 = *(const short8*)qa0; av1 = *(const short8*)qa1;                \
    qa0 += BK; qa1 += BK;                                                \
    _Pragma("unroll")                                                    \
    for (int j = 0; j < 8; ++j) {                                        \
      f1[j] = q1[(size_t)j * DFF_]; f3[j] = q3[(size_t)j * DFF_];        \
    }                                                                    \
    q1 += (size_t)BK * DFF_; q3 += (size_t)BK * DFF_;                    \
  } while (0)

#define F1_WRITE() do {                                                  \
    short8 s1, s3;                                                       \
    _Pragma("unroll")                                                    \
    for (int j = 0; j < 8; ++j) { s1[j] = f2bfs(f1[j]); s3[j] = f2bfs(f3[j]); } \
    *(short8*)((char*)Als + aoff0) = av0;                                \
    *(short8*)((char*)Als + aoff1) = av1;                                \
    *(short8*)((char*)B1s + boff) = s1;                                  \
    *(short8*)((char*)B3s + boff) = s3;                                  \
  } while (0)

#define F1_MFMA() do {                                                   \
    int lsw = SWZ(lane) << 4;                                            \
    short8 af[4];                                                        \
    _Pragma("unroll")                                                    \
    for (int mi = 0; mi < 4; ++mi)                                       \
      af[mi] = *(const short8*)((char*)Als + (((wr << 2) + mi) << 10) + lsw); \
    _Pragma("unroll")                                                    \
    for (int ni = 0; ni < 2; ++ni) {                                     \
      short8 bf1 = *(const short8*)((char*)B1s + (((wc << 1) + ni) << 10) + lsw); \
      short8 bf3 = *(const short8*)((char*)B3s + (((wc << 1) + ni) << 10) + lsw); \
      _Pragma("unroll")                                                  \
      for (int mi = 0; mi < 4; ++mi) {                                   \
        acc1[mi][ni] = __builtin_amdgcn_mfma_f32_16x16x32_bf16(af[mi], bf1, acc1[mi][ni], 0, 0, 0); \
        acc3[mi][ni] = __builtin_amdgcn_mfma_f32_16x16x32_bf16(af[mi], bf3, acc3[mi][ni], 0, 0, 0); \
      }                                                                  \
    }                                                                    \
  } while (0)

  F1_LOAD();
  for (int k0 = BK; k0 < D_; k0 += BK) {
    __syncthreads();
    F1_WRITE();
    __syncthreads();
    F1_LOAD();        // next tile's loads in flight across MFMA
    F1_MFMA();
  }
  __syncthreads();
  F1_WRITE();
  __syncthreads();
  F1_MFMA();

  // epilogue: silu(acc1)*acc3 -> bf16 h ; C: col=lane&15, row=(lane>>4)*4+j
  int lr = (lane >> 4) << 2;
  int lc = lane & 15;
  #pragma unroll
  for (int mi = 0; mi < 4; ++mi) {
    #pragma unroll
    for (int j = 0; j < 4; ++j) {
      int m = m0 + (wr << 6) + (mi << 4) + lr + j;
      if (m < Me) {
        unsigned short* hp = hptr + (size_t)m * DFF_ + n0 + (wc << 5) + lc;
        #pragma unroll
        for (int ni = 0; ni < 2; ++ni) {
          float a = acc1[mi][ni][j];
          float gt = a / (1.f + __expf(-a));
          hp[ni << 4] = (unsigned short)f2bfs(gt * acc3[mi][ni][j]);
        }
      }
    }
  }
}

// ---------------- ffn2: y += w * (h@W2), 128x64 tile ----------------
__global__ __launch_bounds__(256, 4) void ffn2_kernel(
    const unsigned short* __restrict__ h, const float* __restrict__ W2,
    const int* __restrict__ counts, const int* __restrict__ rowtok,
    const float* __restrict__ roww, float* __restrict__ y) {
  // grid 3072 = 192 groups x 16 n-blocks
  int bid = blockIdx.x;
  int u = bid >> 3, r = bid & 7;
  int ni_blk = u % 16;
  int g = (u / 16) * 8 + r;
  int ymb = g % 3, e = g / 3;
  int m0 = ymb * BM;
  int n0 = ni_blk * BN;

  int Me = min(counts[e], PAD_);
  if (m0 >= Me) return;

  const unsigned short* A = h + (size_t)(e * PAD_ + m0) * DFF_;
  const float* Bw = W2 + (size_t)e * DFF_ * D_ + n0;

  __shared__ short Als[BM * BK];
  __shared__ short Bs[BK * BN];

  int tid = threadIdx.x;
  int lane = tid & 63;
  int wv = tid >> 6, wr = wv >> 1, wc = wv & 1;

  int arow = tid >> 2, akseg = tid & 3;
  int ag = (akseg << 4) + (arow & 15);
  int aoff0 = ((arow >> 4) << 10) + (SWZ(ag) << 4);
  int aoff1 = aoff0 + (4 << 10);
  int bc = lane, bks = wv;
  int bg = (bks << 4) + (bc & 15);
  int boff = ((bc >> 4) << 10) + (SWZ(bg) << 4);

  const unsigned short* qa0 = A + (size_t)arow * DFF_ + akseg * 8;
  const unsigned short* qa1 = A + (size_t)(arow + 64) * DFF_ + akseg * 8;
  const float* q2 = Bw + (size_t)(bks * 8) * D_ + bc;

  short8 av0, av1;
  float f2[8];
  f32x4 acc[4][2] = {};

#define F2_LOAD() do {                                                   \
    av0 = *(const short8*)qa0; av1 = *(const short8*)qa1;                \
    qa0 += BK; qa1 += BK;                                                \
    _Pragma("unroll")                                                    \
    for (int j = 0; j < 8; ++j) f2[j] = q2[(size_t)j * D_];              \
    q2 += (size_t)BK * D_;                                               \
  } while (0)

#define F2_WRITE() do {                                                  \
    short8 s2;                                                           \
    _Pragma("unroll")                                                    \
    for (int j = 0; j < 8; ++j) s2[j] = f2bfs(f2[j]);                    \
    *(short8*)((char*)Als + aoff0) = av0;                                \
    *(short8*)((char*)Als + aoff1) = av1;                                \
    *(short8*)((char*)Bs + boff) = s2;                                   \
  } while (0)

#define F2_MFMA() do {                                                   \
    int lsw = SWZ(lane) << 4;                                            \
    short8 af[4];                                                        \
    _Pragma("unroll")                                                    \
    for (int mi = 0; mi < 4; ++mi)                                       \
      af[mi] = *(const short8*)((char*)Als + (((wr << 2) + mi) << 10) + lsw); \
    _Pragma("unroll")                                                    \
    for (int ni = 0; ni < 2; ++ni) {                                     \
      short8 bfr = *(const short8*)((char*)Bs + (((wc << 1) + ni) << 10) + lsw); \
      _Pragma("unroll")                                                  \
      for (int mi = 0; mi < 4; ++mi)                                     \
        acc[mi][ni] = __builtin_amdgcn_mfma_f32_16x16x32_bf16(af[mi], bfr, acc[mi][ni], 0, 0, 0); \
    }                                                                    \
  } while (0)

  F2_LOAD();
  for (int k0 = BK; k0 < DFF_; k0 += BK) {
    __syncthreads();
    F2_WRITE();
    __syncthreads();
    F2_LOAD();
    F2_MFMA();
  }
  __syncthreads();
  F2_WRITE();
  __syncthreads();
  F2_MFMA();

  int lr = (lane >> 4) << 2;
  int lc = lane & 15;
  #pragma unroll
  for (int mi = 0; mi < 4; ++mi) {
    #pragma unroll
    for (int j = 0; j < 4; ++j) {
      int m = m0 + (wr << 6) + (mi << 4) + lr + j;
      if (m < Me) {
        int rw = e * PAD_ + m;
        int t = rowtok[rw];
        float w = roww[rw];
        int b = t >> 11, s = t & (S_ - 1);
        float* yp = y + (size_t)(s * B_ + b) * D_ + n0 + (wc << 5) + lc;
        #pragma unroll
        for (int ni = 0; ni < 2; ++ni)
          atomicAdd(&yp[ni << 4], w * acc[mi][ni][j]);   // exactly 2 adds/elem
      }
    }
  }
}

extern "C" void kernel_launch(void* const* d_in, const int* in_sizes, int n_in,
                              void* d_out, int out_size, void* d_ws, size_t ws_size,
                              hipStream_t stream) {
  const float* x  = (const float*)d_in[0];
  const float* Wg = (const float*)d_in[1];
  const float* W1 = (const float*)d_in[2];
  const float* W3 = (const float*)d_in[3];
  const float* W2 = (const float*)d_in[4];
  float* y = (float*)d_out;
  float* laux = y + (size_t)S_ * B_ * D_;

  char* ws = (char*)d_ws;
  float* probs  = (float*)(ws + OFF_PROBS);
  int*   pe     = (int*)  (ws + OFF_PE);
  float* pw     = (float*)(ws + OFF_PW);
  int*   counts = (int*)  (ws + OFF_COUNTS);
  int*   cursor = (int*)  (ws + OFF_CURSOR);
  float* mesum  = (float*)(ws + OFF_MESUM);
  int*   rowtok = (int*)  (ws + OFF_ROWTOK);
  float* roww   = (float*)(ws + OFF_ROWW);
  unsigned short* xbuf = (unsigned short*)(ws + OFF_XBUF);
  unsigned short* h    = (unsigned short*)(ws + OFF_H);

  hipMemsetAsync(d_out, 0, (size_t)out_size * sizeof(float), stream);
  hipMemsetAsync(counts, 0, 512, stream);  // counts + cursor

  gate_kernel<<<T_ / 8, 256, 0, stream>>>(x, Wg, probs, pe, pw, counts);
  me_kernel<<<E_, 256, 0, stream>>>(probs, mesum);
  finalize_kernel<<<1, 64, 0, stream>>>(counts, mesum, laux);
  scatter_kernel<<<NPAIR_, 64, 0, stream>>>(x, pe, pw, cursor, rowtok, roww, xbuf);
  ffn1_kernel<<<192 * 22, 256, 0, stream>>>(xbuf, W1, W3, counts, h);
  ffn2_kernel<<<192 * 16, 256, 0, stream>>>(h, W2, counts, rowtok, roww, y);
}

// Round 5
// 748.909 us; speedup vs baseline: 1.0265x; 1.0265x over previous
//
#include <hip/hip_runtime.h>
#include <hip/hip_bf16.h>

// MoE E=64, top-2, T=8192, D=1024, DFF=1408. Round 5:
//  - FFN pipeline depth 2: two reg staging sets + LDS double-buffer,
//    one barrier per K-step; loads consumed 2 steps after issue.
//  - Everything else (gate v2, swizzles, XCD clustering) as round 4.

#define S_ 2048
#define B_ 4
#define D_ 1024
#define DFF_ 1408
#define E_ 64
#define T_ 8192
#define KTOP_ 2
#define NPAIR_ (T_*KTOP_)
#define PAD_ 384
#define ROWS_ (E_*PAD_)

#define BM 128
#define BN 64
#define BK 32

typedef __attribute__((ext_vector_type(8))) short short8;
typedef __attribute__((ext_vector_type(4))) float f32x4;
typedef __attribute__((ext_vector_type(4))) unsigned short us4;

// ---------------- workspace layout (bytes) ----------------
constexpr size_t OFF_PROBS  = 0;
constexpr size_t OFF_PE     = OFF_PROBS + (size_t)T_*E_*4;
constexpr size_t OFF_PW     = OFF_PE + (size_t)NPAIR_*4;
constexpr size_t OFF_COUNTS = OFF_PW + (size_t)NPAIR_*4;
constexpr size_t OFF_CURSOR = OFF_COUNTS + 256;
constexpr size_t OFF_MESUM  = OFF_CURSOR + 256;
constexpr size_t OFF_ROWTOK = OFF_MESUM + 256;
constexpr size_t OFF_ROWW   = OFF_ROWTOK + (size_t)ROWS_*4;
constexpr size_t OFF_XBUF   = OFF_ROWW + (size_t)ROWS_*4;
constexpr size_t OFF_H      = OFF_XBUF + (size_t)ROWS_*D_*2;

__device__ __forceinline__ short f2bfs(float f) {
  union { __hip_bfloat16 h; short s; } u;
  u.h = __float2bfloat16(f);
  return u.s;
}

// granule XOR swizzle: g in [0,64) -> conflict-free staging & frag reads
__device__ __forceinline__ int SWZ(int g) { return g ^ (((g >> 4) & 3) << 1); }

// ---------------- gate v2 ----------------
__device__ __forceinline__ float softmax64(float acc, int lane) {
  float m = acc;
  for (int o = 32; o; o >>= 1) m = fmaxf(m, __shfl_xor(m, o));
  float p = expf(acc - m);
  float s = p;
  for (int o = 32; o; o >>= 1) s += __shfl_xor(s, o);
  return p / s;
}

__device__ __forceinline__ void topk_write(float p, int t, int lane,
    float* __restrict__ probs, int* __restrict__ pe, float* __restrict__ pw,
    int* __restrict__ counts) {
  probs[(size_t)t * E_ + lane] = p;
  float v1 = p; int i1 = lane;
  for (int o = 32; o; o >>= 1) {
    float ov = __shfl_xor(v1, o); int oi = __shfl_xor(i1, o);
    if (ov > v1 || (ov == v1 && oi < i1)) { v1 = ov; i1 = oi; }
  }
  float v2 = (lane == i1) ? -1.f : p; int i2 = lane;
  for (int o = 32; o; o >>= 1) {
    float ov = __shfl_xor(v2, o); int oi = __shfl_xor(i2, o);
    if (ov > v2 || (ov == v2 && oi < i2)) { v2 = ov; i2 = oi; }
  }
  if (lane == 0) {
    float wsum = v1 + v2;
    pe[2 * t]     = i1; pw[2 * t]     = v1 / wsum;
    pe[2 * t + 1] = i2; pw[2 * t + 1] = v2 / wsum;
    atomicAdd(&counts[i1], 1);
    atomicAdd(&counts[i2], 1);
  }
}

__global__ __launch_bounds__(256) void gate_kernel(
    const float* __restrict__ x, const float* __restrict__ Wg,
    float* __restrict__ probs, int* __restrict__ pe, float* __restrict__ pw,
    int* __restrict__ counts) {
  int t0 = blockIdx.x * 8;
  int tid = threadIdx.x;
  int lane = tid & 63, wv = tid >> 6;
  __shared__ float tk[8][D_];
  for (int u = tid; u < 8 * (D_ / 4); u += 256) {
    int r = u >> 8, c4 = u & 255;
    int t = t0 + r;
    int b = t >> 11, s = t & (S_ - 1);
    ((float4*)tk[r])[c4] = ((const float4*)(x + (size_t)(s * B_ + b) * D_))[c4];
  }
  __syncthreads();
  const float* tkA = tk[2 * wv];
  const float* tkB = tk[2 * wv + 1];
  float acc0 = 0.f, acc1 = 0.f;
  #pragma unroll 8
  for (int d = 0; d < D_; ++d) {
    float w = Wg[(size_t)d * E_ + lane];
    acc0 += tkA[d] * w;
    acc1 += tkB[d] * w;
  }
  int ta = t0 + 2 * wv, tb = ta + 1;
  float p0 = softmax64(acc0, lane);
  float p1 = softmax64(acc1, lane);
  topk_write(p0, ta, lane, probs, pe, pw, counts);
  topk_write(p1, tb, lane, probs, pe, pw, counts);
}

// ---------------- me reduce ----------------
__global__ __launch_bounds__(256) void me_kernel(const float* __restrict__ probs,
                                                 float* __restrict__ mesum) {
  int e = blockIdx.x, tid = threadIdx.x;
  float a = 0.f;
  for (int t = tid; t < T_; t += 256) a += probs[(size_t)t * E_ + e];
  __shared__ float red[256];
  red[tid] = a; __syncthreads();
  for (int s = 128; s; s >>= 1) {
    if (tid < s) red[tid] += red[tid + s];
    __syncthreads();
  }
  if (tid == 0) mesum[e] = red[0];
}

// ---------------- finalize l_aux ----------------
__global__ __launch_bounds__(64) void finalize_kernel(
    const int* __restrict__ counts, const float* __restrict__ mesum,
    float* __restrict__ laux_out) {
  int lane = threadIdx.x;
  float contrib = (mesum[lane] / (float)T_) * ((float)counts[lane] / (float)(T_ * KTOP_));
  for (int o = 32; o; o >>= 1) contrib += __shfl_xor(contrib, o);
  if (lane == 0) laux_out[0] = (float)E_ * contrib;
}

// ---------------- scatter ----------------
__global__ __launch_bounds__(64) void scatter_kernel(
    const float* __restrict__ x, const int* __restrict__ pe, const float* __restrict__ pw,
    int* __restrict__ cursor, int* __restrict__ rowtok, float* __restrict__ roww,
    unsigned short* __restrict__ xbuf) {
  int p = blockIdx.x;
  int lane = threadIdx.x;
  __shared__ int srow;
  if (lane == 0) {
    int e = pe[p];
    int slot = atomicAdd(&cursor[e], 1);
    int row = (slot < PAD_) ? (e * PAD_ + slot) : -1;
    if (row >= 0) { rowtok[row] = p >> 1; roww[row] = pw[p]; }
    srow = row;
  }
  __syncthreads();
  int row = srow;
  if (row < 0) return;
  int t = p >> 1;
  int b = t >> 11, s = t & (S_ - 1);
  const float4* src = (const float4*)(x + (size_t)(s * B_ + b) * D_);
  unsigned short* dst = xbuf + (size_t)row * D_;
  for (int i = lane; i < D_ / 4; i += 64) {
    float4 v = src[i];
    us4 o;
    o.x = (unsigned short)f2bfs(v.x); o.y = (unsigned short)f2bfs(v.y);
    o.z = (unsigned short)f2bfs(v.z); o.w = (unsigned short)f2bfs(v.w);
    *(us4*)(dst + i * 4) = o;
  }
}

// ---------------- ffn1: h = silu(x@W1) * (x@W3), depth-2 pipeline ----------------
__global__ __launch_bounds__(256, 3) void ffn1_kernel(
    const unsigned short* __restrict__ xbuf, const float* __restrict__ W1,
    const float* __restrict__ W3, const int* __restrict__ counts,
    unsigned short* __restrict__ h) {
  // XCD-clustered decode: grid 4224 = 192 groups (e,y) x 22 n-blocks
  int bid = blockIdx.x;
  int u = bid >> 3, r = bid & 7;
  int ni_blk = u % 22;
  int g = (u / 22) * 8 + r;
  int ymb = g % 3, e = g / 3;
  int m0 = ymb * BM;
  int n0 = ni_blk * BN;

  int Me = min(counts[e], PAD_);
  if (m0 >= Me) return;

  const unsigned short* A = xbuf + (size_t)(e * PAD_ + m0) * D_;
  const float* B1 = W1 + (size_t)e * D_ * DFF_ + n0;
  const float* B3 = W3 + (size_t)e * D_ * DFF_ + n0;
  unsigned short* hptr = h + (size_t)e * PAD_ * DFF_;

  __shared__ short Als[2 * BM * BK];   // 2 x 8KB
  __shared__ short B1s[2 * BK * BN];   // 2 x 4KB
  __shared__ short B3s[2 * BK * BN];   // 2 x 4KB

  int tid = threadIdx.x;
  int lane = tid & 63;
  int wv = tid >> 6, wr = wv >> 1, wc = wv & 1;

  int arow = tid >> 2, akseg = tid & 3;
  int ag = (akseg << 4) + (arow & 15);
  int aoff0 = ((arow >> 4) << 10) + (SWZ(ag) << 4);
  int aoff1 = aoff0 + (4 << 10);
  int bc = lane, bks = wv;
  int bg = (bks << 4) + (bc & 15);
  int boff = ((bc >> 4) << 10) + (SWZ(bg) << 4);

  const unsigned short* qa0 = A + (size_t)arow * D_ + akseg * 8;
  const unsigned short* qa1 = A + (size_t)(arow + 64) * D_ + akseg * 8;
  const float* q1 = B1 + (size_t)(bks * 8) * DFF_ + bc;
  const float* q3 = B3 + (size_t)(bks * 8) * DFF_ + bc;

  short8 av0A, av1A, av0B, av1B;
  float f1A[8], f3A[8], f1B[8], f3B[8];
  f32x4 acc1[4][2] = {};
  f32x4 acc3[4][2] = {};

#define F1_LOAD(SET) do {                                                \
    av0##SET = *(const short8*)qa0; av1##SET = *(const short8*)qa1;      \
    qa0 += BK; qa1 += BK;                                                \
    _Pragma("unroll")                                                    \
    for (int j = 0; j < 8; ++j) {                                        \
      f1##SET[j] = q1[(size_t)j * DFF_]; f3##SET[j] = q3[(size_t)j * DFF_]; \
    }                                                                    \
    q1 += (size_t)BK * DFF_; q3 += (size_t)BK * DFF_;                    \
  } while (0)

#define F1_WRITE(SET, BUF) do {                                          \
    short8 s1, s3;                                                       \
    _Pragma("unroll")                                                    \
    for (int j = 0; j < 8; ++j) {                                        \
      s1[j] = f2bfs(f1##SET[j]); s3[j] = f2bfs(f3##SET[j]);              \
    }                                                                    \
    *(short8*)((char*)Als + (BUF)*8192 + aoff0) = av0##SET;              \
    *(short8*)((char*)Als + (BUF)*8192 + aoff1) = av1##SET;              \
    *(short8*)((char*)B1s + (BUF)*4096 + boff) = s1;                     \
    *(short8*)((char*)B3s + (BUF)*4096 + boff) = s3;                     \
  } while (0)

#define F1_MFMA(BUF) do {                                                \
    int lsw = SWZ(lane) << 4;                                            \
    short8 af[4];                                                        \
    _Pragma("unroll")                                                    \
    for (int mi = 0; mi < 4; ++mi)                                       \
      af[mi] = *(const short8*)((char*)Als + (BUF)*8192 + (((wr << 2) + mi) << 10) + lsw); \
    _Pragma("unroll")                                                    \
    for (int ni = 0; ni < 2; ++ni) {                                     \
      short8 bf1 = *(const short8*)((char*)B1s + (BUF)*4096 + (((wc << 1) + ni) << 10) + lsw); \
      short8 bf3 = *(const short8*)((char*)B3s + (BUF)*4096 + (((wc << 1) + ni) << 10) + lsw); \
      _Pragma("unroll")                                                  \
      for (int mi = 0; mi < 4; ++mi) {                                   \
        acc1[mi][ni] = __builtin_amdgcn_mfma_f32_16x16x32_bf16(af[mi], bf1, acc1[mi][ni], 0, 0, 0); \
        acc3[mi][ni] = __builtin_amdgcn_mfma_f32_16x16x32_bf16(af[mi], bf3, acc3[mi][ni], 0, 0, 0); \
      }                                                                  \
    }                                                                    \
  } while (0)

  // pipeline: tiles 0..31; even tiles -> set A/buf0, odd -> set B/buf1
  F1_LOAD(A);            // t0
  F1_LOAD(B);            // t1
  F1_WRITE(A, 0);        // t0 -> buf0
  F1_LOAD(A);            // t2
  __syncthreads();
  for (int it = 0; it < 14; ++it) {
    F1_WRITE(B, 1); F1_LOAD(B); F1_MFMA(0); __syncthreads();  // w t(2it+1), ld t(2it+3), c t(2it)
    F1_WRITE(A, 0); F1_LOAD(A); F1_MFMA(1); __syncthreads();  // w t(2it+2), ld t(2it+4), c t(2it+1)
  }
  F1_WRITE(B, 1); F1_LOAD(B); F1_MFMA(0); __syncthreads();    // w t29, ld t31, c t28
  F1_WRITE(A, 0); F1_MFMA(1); __syncthreads();                // w t30, c t29
  F1_WRITE(B, 1); F1_MFMA(0); __syncthreads();                // w t31, c t30
  F1_MFMA(1);                                                 // c t31

  // epilogue: silu(acc1)*acc3 -> bf16 h ; C: col=lane&15, row=(lane>>4)*4+j
  int lr = (lane >> 4) << 2;
  int lc = lane & 15;
  #pragma unroll
  for (int mi = 0; mi < 4; ++mi) {
    #pragma unroll
    for (int j = 0; j < 4; ++j) {
      int m = m0 + (wr << 6) + (mi << 4) + lr + j;
      if (m < Me) {
        unsigned short* hp = hptr + (size_t)m * DFF_ + n0 + (wc << 5) + lc;
        #pragma unroll
        for (int ni = 0; ni < 2; ++ni) {
          float a = acc1[mi][ni][j];
          float gt = a / (1.f + __expf(-a));
          hp[ni << 4] = (unsigned short)f2bfs(gt * acc3[mi][ni][j]);
        }
      }
    }
  }
}

// ---------------- ffn2: y += w * (h@W2), depth-2 pipeline ----------------
__global__ __launch_bounds__(256, 4) void ffn2_kernel(
    const unsigned short* __restrict__ h, const float* __restrict__ W2,
    const int* __restrict__ counts, const int* __restrict__ rowtok,
    const float* __restrict__ roww, float* __restrict__ y) {
  // grid 3072 = 192 groups x 16 n-blocks
  int bid = blockIdx.x;
  int u = bid >> 3, r = bid & 7;
  int ni_blk = u % 16;
  int g = (u / 16) * 8 + r;
  int ymb = g % 3, e = g / 3;
  int m0 = ymb * BM;
  int n0 = ni_blk * BN;

  int Me = min(counts[e], PAD_);
  if (m0 >= Me) return;

  const unsigned short* A = h + (size_t)(e * PAD_ + m0) * DFF_;
  const float* Bw = W2 + (size_t)e * DFF_ * D_ + n0;

  __shared__ short Als[2 * BM * BK];   // 2 x 8KB
  __shared__ short Bs[2 * BK * BN];    // 2 x 4KB

  int tid = threadIdx.x;
  int lane = tid & 63;
  int wv = tid >> 6, wr = wv >> 1, wc = wv & 1;

  int arow = tid >> 2, akseg = tid & 3;
  int ag = (akseg << 4) + (arow & 15);
  int aoff0 = ((arow >> 4) << 10) + (SWZ(ag) << 4);
  int aoff1 = aoff0 + (4 << 10);
  int bc = lane, bks = wv;
  int bg = (bks << 4) + (bc & 15);
  int boff = ((bc >> 4) << 10) + (SWZ(bg) << 4);

  const unsigned short* qa0 = A + (size_t)arow * DFF_ + akseg * 8;
  const unsigned short* qa1 = A + (size_t)(arow + 64) * DFF_ + akseg * 8;
  const float* q2 = Bw + (size_t)(bks * 8) * D_ + bc;

  short8 av0A, av1A, av0B, av1B;
  float f2A[8], f2B[8];
  f32x4 acc[4][2] = {};

#define F2_LOAD(SET) do {                                                \
    av0##SET = *(const short8*)qa0; av1##SET = *(const short8*)qa1;      \
    qa0 += BK; qa1 += BK;                                                \
    _Pragma("unroll")                                                    \
    for (int j = 0; j < 8; ++j) f2##SET[j] = q2[(size_t)j * D_];         \
    q2 += (size_t)BK * D_;                                               \
  } while (0)

#define F2_WRITE(SET, BUF) do {                                          \
    short8 s2;                                                           \
    _Pragma("unroll")                                                    \
    for (int j = 0; j < 8; ++j) s2[j] = f2bfs(f2##SET[j]);               \
    *(short8*)((char*)Als + (BUF)*8192 + aoff0) = av0##SET;              \
    *(short8*)((char*)Als + (BUF)*8192 + aoff1) = av1##SET;              \
    *(short8*)((char*)Bs + (BUF)*4096 + boff) = s2;                      \
  } while (0)

#define F2_MFMA(BUF) do {                                                \
    int lsw = SWZ(lane) << 4;                                            \
    short8 af[4];                                                        \
    _Pragma("unroll")                                                    \
    for (int mi = 0; mi < 4; ++mi)                                       \
      af[mi] = *(const short8*)((char*)Als + (BUF)*8192 + (((wr << 2) + mi) << 10) + lsw); \
    _Pragma("unroll")                                                    \
    for (int ni = 0; ni < 2; ++ni) {                                     \
      short8 bfr = *(const short8*)((char*)Bs + (BUF)*4096 + (((wc << 1) + ni) << 10) + lsw); \
      _Pragma("unroll")                                                  \
      for (int mi = 0; mi < 4; ++mi)                                     \
        acc[mi][ni] = __builtin_amdgcn_mfma_f32_16x16x32_bf16(af[mi], bfr, acc[mi][ni], 0, 0, 0); \
    }                                                                    \
  } while (0)

  // tiles 0..43; even -> set A/buf0, odd -> set B/buf1
  F2_LOAD(A);            // t0
  F2_LOAD(B);            // t1
  F2_WRITE(A, 0);        // t0
  F2_LOAD(A);            // t2
  __syncthreads();
  for (int it = 0; it < 20; ++it) {
    F2_WRITE(B, 1); F2_LOAD(B); F2_MFMA(0); __syncthreads();
    F2_WRITE(A, 0); F2_LOAD(A); F2_MFMA(1); __syncthreads();
  }
  F2_WRITE(B, 1); F2_LOAD(B); F2_MFMA(0); __syncthreads();    // w t41, ld t43, c t40
  F2_WRITE(A, 0); F2_MFMA(1); __syncthreads();                // w t42, c t41
  F2_WRITE(B, 1); F2_MFMA(0); __syncthreads();                // w t43, c t42
  F2_MFMA(1);                                                 // c t43

  int lr = (lane >> 4) << 2;
  int lc = lane & 15;
  #pragma unroll
  for (int mi = 0; mi < 4; ++mi) {
    #pragma unroll
    for (int j = 0; j < 4; ++j) {
      int m = m0 + (wr << 6) + (mi << 4) + lr + j;
      if (m < Me) {
        int rw = e * PAD_ + m;
        int t = rowtok[rw];
        float w = roww[rw];
        int b = t >> 11, s = t & (S_ - 1);
        float* yp = y + (size_t)(s * B_ + b) * D_ + n0 + (wc << 5) + lc;
        #pragma unroll
        for (int ni = 0; ni < 2; ++ni)
          atomicAdd(&yp[ni << 4], w * acc[mi][ni][j]);   // exactly 2 adds/elem
      }
    }
  }
}

extern "C" void kernel_launch(void* const* d_in, const int* in_sizes, int n_in,
                              void* d_out, int out_size, void* d_ws, size_t ws_size,
                              hipStream_t stream) {
  const float* x  = (const float*)d_in[0];
  const float* Wg = (const float*)d_in[1];
  const float* W1 = (const float*)d_in[2];
  const float* W3 = (const float*)d_in[3];
  const float* W2 = (const float*)d_in[4];
  float* y = (float*)d_out;
  float* laux = y + (size_t)S_ * B_ * D_;

  char* ws = (char*)d_ws;
  float* probs  = (float*)(ws + OFF_PROBS);
  int*   pe     = (int*)  (ws + OFF_PE);
  float* pw     = (float*)(ws + OFF_PW);
  int*   counts = (int*)  (ws + OFF_COUNTS);
  int*   cursor = (int*)  (ws + OFF_CURSOR);
  float* mesum  = (float*)(ws + OFF_MESUM);
  int*   rowtok = (int*)  (ws + OFF_ROWTOK);
  float* roww   = (float*)(ws + OFF_ROWW);
  unsigned short* xbuf = (unsigned short*)(ws + OFF_XBUF);
  unsigned short* h    = (unsigned short*)(ws + OFF_H);

  hipMemsetAsync(d_out, 0, (size_t)out_size * sizeof(float), stream);
  hipMemsetAsync(counts, 0, 512, stream);  // counts + cursor

  gate_kernel<<<T_ / 8, 256, 0, stream>>>(x, Wg, probs, pe, pw, counts);
  me_kernel<<<E_, 256, 0, stream>>>(probs, mesum);
  finalize_kernel<<<1, 64, 0, stream>>>(counts, mesum, laux);
  scatter_kernel<<<NPAIR_, 64, 0, stream>>>(x, pe, pw, cursor, rowtok, roww, xbuf);
  ffn1_kernel<<<192 * 22, 256, 0, stream>>>(xbuf, W1, W3, counts, h);
  ffn2_kernel<<<192 * 16, 256, 0, stream>>>(h, W2, counts, rowtok, roww, y);
}